// Round 17
// baseline (477.188 us; speedup 1.0000x reference)
//
#include <hip/hip_runtime.h>

// ---------------------------------------------------------------------------
// DepTreeLSTM on MI355X — round 17: R15 with 1-tree/block fused (occupancy).
//   fused_kernel: {leaf, lvl1} per 1 tree, 4096 blocks, LDS 40 KB ->
//   3 blocks/CU at bounds(512,6) (was 2 trees / 80 KB / 2 blocks, occ 42%).
//   Phase structure, staging, numerics identical to R15; only MT halved.
//   Tails lvl2..5: R12/R15 lvl_kernel verbatim (R16's pair fusion spilled).
// ws: BTf bf16 fragment-packed at 0; c-state f32 [N][128] at 1MB.
// ---------------------------------------------------------------------------

typedef float f32x4 __attribute__((ext_vector_type(4)));
typedef __bf16 bf16x8 __attribute__((ext_vector_type(8)));
typedef unsigned short u16x8 __attribute__((ext_vector_type(8)));

__device__ __forceinline__ unsigned short f2bf(float x) {
  union { __bf16 b; unsigned short u; } cv;
  cv.b = (__bf16)x;
  return cv.u;
}
__device__ __forceinline__ float bf2f(unsigned short u) {
  return __uint_as_float(((unsigned int)u) << 16);
}
__device__ __forceinline__ float sigf(float x) { return 1.f / (1.f + __expf(-x)); }
__device__ __forceinline__ float tanhfast(float x) {
  return 1.f - 2.f / (__expf(2.f * x) + 1.f);
}

// Pack B in fragment order: BTf[((tile*16 + ks)*64 + lane)*8 + j]
// lane = kq*16 + cl, col = tile*16+cl, k = ks*32 + kq*8 + j  (K=512).
// col<384: W_iou/U_iou; col>=384: W_f (dup f0/f1) / U_f_w.
__global__ void prep_kernel(const float* __restrict__ Wi, const float* __restrict__ Ui,
                            const float* __restrict__ Wf, const float* __restrict__ Uf,
                            unsigned short* __restrict__ BTf) {
  int idx = blockIdx.x * 256 + threadIdx.x;
  int j = idx & 7;
  int lane = (idx >> 3) & 63;
  int ks = (idx >> 9) & 15;
  int tile = idx >> 13;
  int cl = lane & 15, kq = lane >> 4;
  int col = tile * 16 + cl;
  int k = ks * 32 + kq * 8 + j;
  float v;
  if (k < 256) {
    v = (col < 384) ? Wi[k * 384 + col] : Wf[k * 128 + ((col - 384) & 127)];
  } else {
    int kk = k & 255;
    v = (col < 384) ? Ui[kk * 384 + col] : Uf[kk * 256 + (col - 384)];
  }
  BTf[idx] = f2bf(v);
}

// A-LDS fragment-order address (elements): ((mt*NKS + ks)*64 + kq*16 + r)*8 + j
template <int NKS>
__device__ __forceinline__ int a_addr(int rblk, int k) {
  int mt = rblk >> 4, r = rblk & 15;
  int ks = k >> 5, kq = (k >> 3) & 3, j = k & 7;
  return (((mt * NKS + ks) * 64 + (kq << 4) + r) << 3) + j;
}

// ======================= fused leaf + lvl1 kernel (1 tree) =================
__global__ __launch_bounds__(512, 6) void fused_kernel(
    const float* __restrict__ emb, const float* __restrict__ cmask,
    const int* __restrict__ ctype,
    const unsigned short* __restrict__ BTf,
    const float* __restrict__ b_iou, const float* __restrict__ ufb,
    const float* __restrict__ bf_,
    float* __restrict__ hout, float* __restrict__ cbuf) {
  __shared__ unsigned short Alds[8192];    // 16 KB: leaf 32xK256 / lvl1 16xK512
  __shared__ unsigned short hstash[4096];  // 8 KB: 32 leaves x 128 bf16
  __shared__ float cstash[4096];           // 16 KB: 32 leaves x 128 f32

  const int tid = threadIdx.x;
  const int lane = tid & 63;
  const int w = tid >> 6;
  const int cl = lane & 15;
  const int rb = (lane >> 4) << 2;
  const int hcol = w * 16 + cl;
  const int g0 = blockIdx.x * 63;        // one tree

  const unsigned short* Bw = BTf + (size_t)w * 8192 + lane * 8;

  // ---- Phase 0 staging: 32 leaf emb rows, fragment image (NKS=8) ----
#pragma unroll
  for (int c = 0; c < 2; ++c) {
    const int ks_e = tid >> 6;
    const int lq = tid & 63;
    const int k0 = ks_e * 32 + (lq >> 4) * 8;
    const int rblk = c * 16 + (lq & 15);
    const int g = g0 + rblk;             // leaves are nodes 0..31
    const float4 v0 = *(const float4*)&emb[(size_t)g * 256 + k0];
    const float4 v1 = *(const float4*)&emb[(size_t)g * 256 + k0 + 4];
    ushort4 p0, p1;
    p0.x = f2bf(v0.x); p0.y = f2bf(v0.y); p0.z = f2bf(v0.z); p0.w = f2bf(v0.w);
    p1.x = f2bf(v1.x); p1.y = f2bf(v1.y); p1.z = f2bf(v1.z); p1.w = f2bf(v1.w);
    unsigned short* dst = &Alds[((c * 8 + ks_e) * 64 + lq) * 8];
    *(ushort4*)dst = p0;
    *(ushort4*)(dst + 4) = p1;
  }
  __syncthreads();

  // ---- Phase 0 GEMM: MT=2, NT=3, slices 0..7 ----
  {
    f32x4 acc[2][3];
#pragma unroll
    for (int mt = 0; mt < 2; ++mt)
#pragma unroll
      for (int t = 0; t < 3; ++t) acc[mt][t] = (f32x4){0.f, 0.f, 0.f, 0.f};
    bf16x8 bA[3], bB[3];
#pragma unroll
    for (int t = 0; t < 3; ++t) bA[t] = *(const bf16x8*)&Bw[(size_t)t * 65536];
    auto step0 = [&](bf16x8(&cur)[3], bf16x8(&nxt)[3], int ks) {
      if (ks + 1 < 8) {
#pragma unroll
        for (int t = 0; t < 3; ++t)
          nxt[t] = *(const bf16x8*)&Bw[(size_t)t * 65536 + (ks + 1) * 512];
      }
      __builtin_amdgcn_s_setprio(1);
#pragma unroll
      for (int mt = 0; mt < 2; ++mt) {
        const bf16x8 a = *(const bf16x8*)&Alds[((mt * 8 + ks) * 64 + lane) << 3];
#pragma unroll
        for (int t = 0; t < 3; ++t)
          acc[mt][t] = __builtin_amdgcn_mfma_f32_16x16x32_bf16(a, cur[t], acc[mt][t], 0, 0, 0);
      }
      __builtin_amdgcn_s_setprio(0);
    };
#pragma unroll
    for (int ks2 = 0; ks2 < 4; ++ks2) {
      step0(bA, bB, 2 * ks2);
      step0(bB, bA, 2 * ks2 + 1);
    }
    // ---- Phase 0 epilogue: h->hout+hstash, c->cstash only ----
    const float bi = b_iou[hcol], bo = b_iou[128 + hcol], bu = b_iou[256 + hcol];
#pragma unroll
    for (int mt = 0; mt < 2; ++mt) {
#pragma unroll
      for (int r = 0; r < 4; ++r) {
        const int row = (mt << 4) + rb + r;   // 0..31
        const int g = g0 + row;
        const float cn = sigf(acc[mt][0][r] + bi) * tanhfast(acc[mt][2][r] + bu);
        const float hn = sigf(acc[mt][1][r] + bo) * tanhfast(cn);
        hout[(size_t)g * 128 + hcol] = hn;
        hstash[row * 128 + hcol] = f2bf(hn);
        cstash[row * 128 + hcol] = cn;
      }
    }
  }
  __syncthreads();   // stash visible; Alds free for reuse

  // ---- Phase 1 staging: 16 lvl1 rows, K=512 fragment image (NKS=16) ----
  {  // emb part (k<256): 16 rows x 32 subs = 512 items exactly
    const int rblk = tid >> 5, sub = tid & 31;
    const int g = g0 + 32 + rblk;
    const int k0 = sub * 8;
    const float4 v0 = *(const float4*)&emb[(size_t)g * 256 + k0];
    const float4 v1 = *(const float4*)&emb[(size_t)g * 256 + k0 + 4];
    ushort4 p0, p1;
    p0.x = f2bf(v0.x); p0.y = f2bf(v0.y); p0.z = f2bf(v0.z); p0.w = f2bf(v0.w);
    p1.x = f2bf(v1.x); p1.y = f2bf(v1.y); p1.z = f2bf(v1.z); p1.w = f2bf(v1.w);
    unsigned short* dst = &Alds[a_addr<16>(rblk, k0)];
    *(ushort4*)dst = p0;
    *(ushort4*)(dst + 4) = p1;
  }
  // ht part (k 256..511) from hstash: 16 threads/row, 8 cols each
  if (tid < 256) {
    const int rblk = tid >> 4, q = tid & 15;   // rblk 0..15
    const int gp = g0 + 32 + rblk;
    const int ch0 = 2 * rblk, ch1 = ch0 + 1;   // leaf stash rows
    const int ty0 = ctype[2 * gp], ty1 = ctype[2 * gp + 1];
    const float c0 = cmask[2 * gp], c1 = cmask[2 * gp + 1];
    const float w00 = (ty0 == 0) ? c0 : 0.f, w01 = (ty1 == 0) ? c1 : 0.f;
    const float w10 = (ty0 == 1) ? c0 : 0.f, w11 = (ty1 == 1) ? c1 : 0.f;
    const int jc = q * 8;
    const u16x8 va = *(const u16x8*)&hstash[ch0 * 128 + jc];
    const u16x8 vb = *(const u16x8*)&hstash[ch1 * 128 + jc];
    u16x8 o0, o1;
#pragma unroll
    for (int e = 0; e < 8; ++e) {
      const float fa = bf2f(va[e]), fb = bf2f(vb[e]);
      o0[e] = f2bf(w00 * fa + w01 * fb);
      o1[e] = f2bf(w10 * fa + w11 * fb);
    }
    *(u16x8*)&Alds[a_addr<16>(rblk, 256 + jc)] = o0;
    *(u16x8*)&Alds[a_addr<16>(rblk, 384 + jc)] = o1;
  }
  __syncthreads();

  // ---- Phase 1 GEMM: MT=1, NT=5, slices 0..15 ----
  {
    f32x4 acc[1][5];
#pragma unroll
    for (int t = 0; t < 5; ++t) acc[0][t] = (f32x4){0.f, 0.f, 0.f, 0.f};
    bf16x8 bA[5], bB[5];
#pragma unroll
    for (int t = 0; t < 5; ++t) bA[t] = *(const bf16x8*)&Bw[(size_t)t * 65536];
    auto step1 = [&](bf16x8(&cur)[5], bf16x8(&nxt)[5], int ks) {
      if (ks + 1 < 16) {
#pragma unroll
        for (int t = 0; t < 5; ++t)
          nxt[t] = *(const bf16x8*)&Bw[(size_t)t * 65536 + (ks + 1) * 512];
      }
      __builtin_amdgcn_s_setprio(1);
      const bf16x8 a = *(const bf16x8*)&Alds[(ks * 64 + lane) << 3];
#pragma unroll
      for (int t = 0; t < 5; ++t)
        acc[0][t] = __builtin_amdgcn_mfma_f32_16x16x32_bf16(a, cur[t], acc[0][t], 0, 0, 0);
      __builtin_amdgcn_s_setprio(0);
    };
#pragma unroll
    for (int ks2 = 0; ks2 < 8; ++ks2) {
      step1(bA, bB, 2 * ks2);
      step1(bB, bA, 2 * ks2 + 1);
    }
    // ---- Phase 1 epilogue ----
    const float bi = b_iou[hcol], bo = b_iou[128 + hcol], bu = b_iou[256 + hcol];
    const float f0b = ufb[hcol], f1b = ufb[128 + hcol], bfv = bf_[hcol];
#pragma unroll
    for (int r = 0; r < 4; ++r) {
      const int row = rb + r;                  // 0..15
      const int g = g0 + 32 + row;
      const int ch0 = 2 * row, ch1 = ch0 + 1;  // stash rows
      const int ty0 = ctype[2 * g], ty1 = ctype[2 * g + 1];
      const float c0v = cmask[2 * g], c1v = cmask[2 * g + 1];
      const float iv = acc[0][0][r] + bi;
      const float ov = acc[0][1][r] + bo;
      const float uv = acc[0][2][r] + bu;
      const float f0 = acc[0][3][r] + f0b;
      const float f1 = acc[0][4][r] + f1b;
      const float fa = (ty0 == 0) ? f0 : f1;
      const float fb = (ty1 == 0) ? f0 : f1;
      const float ft0 = sigf(fa + bfv);
      const float ft1 = sigf(fb + bfv);
      const float ccell = ft0 * cstash[ch0 * 128 + hcol] * c0v +
                          ft1 * cstash[ch1 * 128 + hcol] * c1v;
      const float cn = sigf(iv) * tanhfast(uv) + ccell;
      const float hn = sigf(ov) * tanhfast(cn);
      cbuf[(size_t)g * 128 + hcol] = cn;   // read by lvl2 tail
      hout[(size_t)g * 128 + hcol] = hn;
    }
  }
}

// ======================= tail levels (R12/R15 verbatim) ====================
template <bool LEAF, int MT, int WPE>
__global__ __launch_bounds__(512, WPE) void lvl_kernel(
    const float* __restrict__ emb, const float* __restrict__ cmask,
    const int* __restrict__ cidx, const int* __restrict__ ctype,
    const unsigned short* __restrict__ BTf,
    const float* __restrict__ b_iou, const float* __restrict__ ufb,
    const float* __restrict__ bf_,
    float* __restrict__ hout, float* __restrict__ cbuf,
    int lc, int cntm1, int offs) {
  constexpr int KD = LEAF ? 256 : 512;
  constexpr int NKS = KD / 32;
  constexpr int NT = LEAF ? 3 : 5;
  constexpr int ROWS = MT * 16;
  __shared__ unsigned short Alds[ROWS * KD];

  const int tid = threadIdx.x;
  const int lane = tid & 63;
  const int w = tid >> 6;
  const int m0 = blockIdx.x * ROWS;

#pragma unroll
  for (int c = 0; c < MT; ++c) {
    const int ks_e = tid >> 6;
    const int lq = tid & 63;
    const int k0 = ks_e * 32 + (lq >> 4) * 8;
    const int rblk = c * 16 + (lq & 15);
    const int m = m0 + rblk;
    const int g = ((m >> lc) * 63) + offs + (m & cntm1);
    const float4 v0 = *(const float4*)&emb[(size_t)g * 256 + k0];
    const float4 v1 = *(const float4*)&emb[(size_t)g * 256 + k0 + 4];
    ushort4 p0, p1;
    p0.x = f2bf(v0.x); p0.y = f2bf(v0.y); p0.z = f2bf(v0.z); p0.w = f2bf(v0.w);
    p1.x = f2bf(v1.x); p1.y = f2bf(v1.y); p1.z = f2bf(v1.z); p1.w = f2bf(v1.w);
    unsigned short* dst = &Alds[((c * NKS + ks_e) * 64 + lq) * 8];
    *(ushort4*)dst = p0;
    *(ushort4*)(dst + 4) = p1;
  }

  if (!LEAF) {
    constexpr int TPR = 512 / ROWS;
    constexpr int CPT = 128 / TPR;
    const int rblk = tid / TPR, q = tid % TPR;
    const int m = m0 + rblk;
    const int g = ((m >> lc) * 63) + offs + (m & cntm1);
    const int ch0 = cidx[2 * g], ch1 = cidx[2 * g + 1];
    const int ty0 = ctype[2 * g], ty1 = ctype[2 * g + 1];
    const float c0 = cmask[2 * g], c1 = cmask[2 * g + 1];
    const float w00 = (ty0 == 0) ? c0 : 0.f, w01 = (ty1 == 0) ? c1 : 0.f;
    const float w10 = (ty0 == 1) ? c0 : 0.f, w11 = (ty1 == 1) ? c1 : 0.f;
#pragma unroll
    for (int jj = 0; jj < CPT / 4; ++jj) {
      const int j = q * CPT + jj * 4;
      float4 a = *(const float4*)&hout[(size_t)ch0 * 128 + j];
      float4 b = *(const float4*)&hout[(size_t)ch1 * 128 + j];
      ushort4 p0, p1;
      p0.x = f2bf(w00 * a.x + w01 * b.x);
      p0.y = f2bf(w00 * a.y + w01 * b.y);
      p0.z = f2bf(w00 * a.z + w01 * b.z);
      p0.w = f2bf(w00 * a.w + w01 * b.w);
      p1.x = f2bf(w10 * a.x + w11 * b.x);
      p1.y = f2bf(w10 * a.y + w11 * b.y);
      p1.z = f2bf(w10 * a.z + w11 * b.z);
      p1.w = f2bf(w10 * a.w + w11 * b.w);
      *(ushort4*)&Alds[a_addr<NKS>(rblk, 256 + j)] = p0;
      *(ushort4*)&Alds[a_addr<NKS>(rblk, 384 + j)] = p1;
    }
  }
  __syncthreads();

  f32x4 acc[MT][NT];
#pragma unroll
  for (int mt = 0; mt < MT; ++mt)
#pragma unroll
    for (int t = 0; t < NT; ++t) acc[mt][t] = (f32x4){0.f, 0.f, 0.f, 0.f};

  const unsigned short* Bw = BTf + (size_t)w * 8192 + lane * 8;
  bf16x8 bA[NT], bB[NT];
#pragma unroll
  for (int t = 0; t < NT; ++t)
    bA[t] = *(const bf16x8*)&Bw[(size_t)t * 65536];

  auto step = [&](bf16x8(&cur)[NT], bf16x8(&nxt)[NT], int ks) {
    if (ks + 1 < NKS) {
#pragma unroll
      for (int t = 0; t < NT; ++t)
        nxt[t] = *(const bf16x8*)&Bw[(size_t)t * 65536 + (ks + 1) * 512];
    }
    __builtin_amdgcn_s_setprio(1);
#pragma unroll
    for (int mt = 0; mt < MT; ++mt) {
      const bf16x8 a = *(const bf16x8*)&Alds[((mt * NKS + ks) * 64 + lane) << 3];
#pragma unroll
      for (int t = 0; t < NT; ++t)
        acc[mt][t] = __builtin_amdgcn_mfma_f32_16x16x32_bf16(a, cur[t], acc[mt][t], 0, 0, 0);
    }
    __builtin_amdgcn_s_setprio(0);
  };
#pragma unroll
  for (int ks2 = 0; ks2 < NKS / 2; ++ks2) {
    step(bA, bB, 2 * ks2);
    step(bB, bA, 2 * ks2 + 1);
  }

  const int cl = lane & 15;
  const int rb = (lane >> 4) << 2;
  const int hcol = w * 16 + cl;
  const float bi = b_iou[hcol];
  const float bo = b_iou[128 + hcol];
  const float bu = b_iou[256 + hcol];
  float f0b = 0.f, f1b = 0.f, bfv = 0.f;
  if (!LEAF) { f0b = ufb[hcol]; f1b = ufb[128 + hcol]; bfv = bf_[hcol]; }

#pragma unroll
  for (int mt = 0; mt < MT; ++mt) {
#pragma unroll
    for (int r = 0; r < 4; ++r) {
      const int m = m0 + (mt << 4) + rb + r;
      const int g = ((m >> lc) * 63) + offs + (m & cntm1);
      const float iv = acc[mt][0][r] + bi;
      const float ov = acc[mt][1][r] + bo;
      const float uv = acc[mt][2][r] + bu;
      float cn;
      if (LEAF) {
        cn = sigf(iv) * tanhfast(uv);
      } else {
        const int ch0 = cidx[2 * g], ch1 = cidx[2 * g + 1];
        const int ty0 = ctype[2 * g], ty1 = ctype[2 * g + 1];
        const float c0v = cmask[2 * g], c1v = cmask[2 * g + 1];
        const float f0 = acc[mt][3][r] + f0b;
        const float f1 = acc[mt][4][r] + f1b;
        const float fa = (ty0 == 0) ? f0 : f1;
        const float fb = (ty1 == 0) ? f0 : f1;
        const float ft0 = sigf(fa + bfv);
        const float ft1 = sigf(fb + bfv);
        const float ccell = ft0 * cbuf[(size_t)ch0 * 128 + hcol] * c0v +
                            ft1 * cbuf[(size_t)ch1 * 128 + hcol] * c1v;
        cn = sigf(iv) * tanhfast(uv) + ccell;
      }
      const float hn = sigf(ov) * tanhfast(cn);
      cbuf[(size_t)g * 128 + hcol] = cn;
      hout[(size_t)g * 128 + hcol] = hn;
    }
  }
}

extern "C" void kernel_launch(void* const* d_in, const int* in_sizes, int n_in,
                              void* d_out, int out_size, void* d_ws, size_t ws_size,
                              hipStream_t stream) {
  (void)in_sizes; (void)n_in; (void)out_size; (void)ws_size;
  const float* emb   = (const float*)d_in[0];
  const float* cmask = (const float*)d_in[1];
  const float* W_iou = (const float*)d_in[2];
  const float* U_iou = (const float*)d_in[3];
  const float* b_iou = (const float*)d_in[4];
  const float* W_f   = (const float*)d_in[5];
  const float* U_f_w = (const float*)d_in[6];
  const float* U_f_b = (const float*)d_in[7];
  const float* b_f   = (const float*)d_in[8];
  const int* cidx    = (const int*)d_in[9];
  const int* ctype   = (const int*)d_in[10];
  float* hout = (float*)d_out;

  unsigned short* BTf = (unsigned short*)d_ws;                // 655360 B
  float* cbuf = (float*)((char*)d_ws + (size_t)(1 << 20));    // 132 MB

  prep_kernel<<<1280, 256, 0, stream>>>(W_iou, U_iou, W_f, U_f_w, BTf);

  // {leaf, lvl1}: 1 tree/block, 3 blocks/CU
  fused_kernel<<<4096, 512, 0, stream>>>(emb, cmask, ctype, BTf, b_iou,
                                         U_f_b, b_f, hout, cbuf);
  // levels 2..5 (R12/R15 tails)
  lvl_kernel<false, 2, 4><<<1024, 512, 0, stream>>>(emb, cmask, cidx, ctype, BTf, b_iou,
                                                    U_f_b, b_f, hout, cbuf, 3, 7, 48);
  lvl_kernel<false, 2, 4><<<512, 512, 0, stream>>>(emb, cmask, cidx, ctype, BTf, b_iou,
                                                   U_f_b, b_f, hout, cbuf, 2, 3, 56);
  lvl_kernel<false, 1, 4><<<512, 512, 0, stream>>>(emb, cmask, cidx, ctype, BTf, b_iou,
                                                   U_f_b, b_f, hout, cbuf, 1, 1, 60);
  lvl_kernel<false, 1, 4><<<256, 512, 0, stream>>>(emb, cmask, cidx, ctype, BTf, b_iou,
                                                   U_f_b, b_f, hout, cbuf, 0, 0, 62);
}

// Round 18
// 399.842 us; speedup vs baseline: 1.1934x; 1.1934x over previous
//
#include <hip/hip_runtime.h>

// ---------------------------------------------------------------------------
// DepTreeLSTM on MI355X — round 18: fused {leaf, lvl1, lvl2} per 2 trees.
//   Phase 0: leaf GEMM (MT=4, K=256, NT=3); h->hout + hstash; c->cstash.
//   Phase 1: lvl1 GEMM (MT=2, K=512, NT=5); children from stash rows 0..63;
//            epilogue HOISTS leaf-c reads (sched_barrier fence), then writes
//            lvl1 h->hout + stash rows 0..31, c->stash ONLY (cbuf write gone).
//   Phase 2: lvl2 GEMM (MT=1, K=512, NT=5); children from stash rows 0..31;
//            h->hout, c->cbuf (read by lvl3 tail).
// Tails lvl3..5: R12/R15 lvl_kernel verbatim.
// LDS: A 32K + hstash 16K + cstash 32K = 80 KB -> 2 blocks/CU.
// ws: BTf bf16 fragment-packed at 0; c-state f32 [N][128] at 1MB.
// ---------------------------------------------------------------------------

typedef float f32x4 __attribute__((ext_vector_type(4)));
typedef __bf16 bf16x8 __attribute__((ext_vector_type(8)));
typedef unsigned short u16x8 __attribute__((ext_vector_type(8)));

__device__ __forceinline__ unsigned short f2bf(float x) {
  union { __bf16 b; unsigned short u; } cv;
  cv.b = (__bf16)x;
  return cv.u;
}
__device__ __forceinline__ float bf2f(unsigned short u) {
  return __uint_as_float(((unsigned int)u) << 16);
}
__device__ __forceinline__ float sigf(float x) { return 1.f / (1.f + __expf(-x)); }
__device__ __forceinline__ float tanhfast(float x) {
  return 1.f - 2.f / (__expf(2.f * x) + 1.f);
}

// Pack B in fragment order: BTf[((tile*16 + ks)*64 + lane)*8 + j]
// lane = kq*16 + cl, col = tile*16+cl, k = ks*32 + kq*8 + j  (K=512).
// col<384: W_iou/U_iou; col>=384: W_f (dup f0/f1) / U_f_w.
__global__ void prep_kernel(const float* __restrict__ Wi, const float* __restrict__ Ui,
                            const float* __restrict__ Wf, const float* __restrict__ Uf,
                            unsigned short* __restrict__ BTf) {
  int idx = blockIdx.x * 256 + threadIdx.x;
  int j = idx & 7;
  int lane = (idx >> 3) & 63;
  int ks = (idx >> 9) & 15;
  int tile = idx >> 13;
  int cl = lane & 15, kq = lane >> 4;
  int col = tile * 16 + cl;
  int k = ks * 32 + kq * 8 + j;
  float v;
  if (k < 256) {
    v = (col < 384) ? Wi[k * 384 + col] : Wf[k * 128 + ((col - 384) & 127)];
  } else {
    int kk = k & 255;
    v = (col < 384) ? Ui[kk * 384 + col] : Uf[kk * 256 + (col - 384)];
  }
  BTf[idx] = f2bf(v);
}

// A-LDS fragment-order address (elements): ((mt*NKS + ks)*64 + kq*16 + r)*8 + j
template <int NKS>
__device__ __forceinline__ int a_addr(int rblk, int k) {
  int mt = rblk >> 4, r = rblk & 15;
  int ks = k >> 5, kq = (k >> 3) & 3, j = k & 7;
  return (((mt * NKS + ks) * 64 + (kq << 4) + r) << 3) + j;
}

// ======================= fused leaf + lvl1 + lvl2 kernel ===================
__global__ __launch_bounds__(512, 4) void fused_kernel(
    const float* __restrict__ emb, const float* __restrict__ cmask,
    const int* __restrict__ ctype,
    const unsigned short* __restrict__ BTf,
    const float* __restrict__ b_iou, const float* __restrict__ ufb,
    const float* __restrict__ bf_,
    float* __restrict__ hout, float* __restrict__ cbuf) {
  __shared__ unsigned short Alds[16384];   // 32 KB
  __shared__ unsigned short hstash[8192];  // 16 KB: 64 rows x 128 bf16
  __shared__ float cstash[8192];           // 32 KB: 64 rows x 128 f32

  const int tid = threadIdx.x;
  const int lane = tid & 63;
  const int w = tid >> 6;
  const int cl = lane & 15;
  const int rb = (lane >> 4) << 2;
  const int hcol = w * 16 + cl;
  const int g0 = blockIdx.x * 126;       // two trees

  const unsigned short* Bw = BTf + (size_t)w * 8192 + lane * 8;

  // ---- Phase 0 staging: 64 leaf emb rows, fragment image (NKS=8) ----
#pragma unroll
  for (int c = 0; c < 4; ++c) {
    const int ks_e = tid >> 6;
    const int lq = tid & 63;
    const int k0 = ks_e * 32 + (lq >> 4) * 8;
    const int rblk = c * 16 + (lq & 15);
    const int g = g0 + (rblk >> 5) * 63 + (rblk & 31);
    const float4 v0 = *(const float4*)&emb[(size_t)g * 256 + k0];
    const float4 v1 = *(const float4*)&emb[(size_t)g * 256 + k0 + 4];
    ushort4 p0, p1;
    p0.x = f2bf(v0.x); p0.y = f2bf(v0.y); p0.z = f2bf(v0.z); p0.w = f2bf(v0.w);
    p1.x = f2bf(v1.x); p1.y = f2bf(v1.y); p1.z = f2bf(v1.z); p1.w = f2bf(v1.w);
    unsigned short* dst = &Alds[((c * 8 + ks_e) * 64 + lq) * 8];
    *(ushort4*)dst = p0;
    *(ushort4*)(dst + 4) = p1;
  }
  __syncthreads();

  // ---- Phase 0 GEMM: MT=4, NT=3, slices 0..7 ----
  {
    f32x4 acc[4][3];
#pragma unroll
    for (int mt = 0; mt < 4; ++mt)
#pragma unroll
      for (int t = 0; t < 3; ++t) acc[mt][t] = (f32x4){0.f, 0.f, 0.f, 0.f};
    bf16x8 bA[3], bB[3];
#pragma unroll
    for (int t = 0; t < 3; ++t) bA[t] = *(const bf16x8*)&Bw[(size_t)t * 65536];
    auto step0 = [&](bf16x8(&cur)[3], bf16x8(&nxt)[3], int ks) {
      if (ks + 1 < 8) {
#pragma unroll
        for (int t = 0; t < 3; ++t)
          nxt[t] = *(const bf16x8*)&Bw[(size_t)t * 65536 + (ks + 1) * 512];
      }
      __builtin_amdgcn_s_setprio(1);
#pragma unroll
      for (int mt = 0; mt < 4; ++mt) {
        const bf16x8 a = *(const bf16x8*)&Alds[((mt * 8 + ks) * 64 + lane) << 3];
#pragma unroll
        for (int t = 0; t < 3; ++t)
          acc[mt][t] = __builtin_amdgcn_mfma_f32_16x16x32_bf16(a, cur[t], acc[mt][t], 0, 0, 0);
      }
      __builtin_amdgcn_s_setprio(0);
    };
#pragma unroll
    for (int ks2 = 0; ks2 < 4; ++ks2) {
      step0(bA, bB, 2 * ks2);
      step0(bB, bA, 2 * ks2 + 1);
    }
    const float bi = b_iou[hcol], bo = b_iou[128 + hcol], bu = b_iou[256 + hcol];
#pragma unroll
    for (int mt = 0; mt < 4; ++mt) {
#pragma unroll
      for (int r = 0; r < 4; ++r) {
        const int row = (mt << 4) + rb + r;
        const int g = g0 + (row >> 5) * 63 + (row & 31);
        const float cn = sigf(acc[mt][0][r] + bi) * tanhfast(acc[mt][2][r] + bu);
        const float hn = sigf(acc[mt][1][r] + bo) * tanhfast(cn);
        hout[(size_t)g * 128 + hcol] = hn;
        hstash[row * 128 + hcol] = f2bf(hn);
        cstash[row * 128 + hcol] = cn;
      }
    }
  }
  __syncthreads();   // leaf stash visible

  // ---- Phase 1 staging: 32 lvl1 rows, K=512 fragment image (NKS=16) ----
#pragma unroll
  for (int c = 0; c < 2; ++c) {
    const int ks_e = tid >> 6;
    const int lq = tid & 63;
    const int k0 = ks_e * 32 + (lq >> 4) * 8;
    const int rblk = c * 16 + (lq & 15);
    const int g = g0 + (rblk >> 4) * 63 + 32 + (rblk & 15);
    const float4 v0 = *(const float4*)&emb[(size_t)g * 256 + k0];
    const float4 v1 = *(const float4*)&emb[(size_t)g * 256 + k0 + 4];
    ushort4 p0, p1;
    p0.x = f2bf(v0.x); p0.y = f2bf(v0.y); p0.z = f2bf(v0.z); p0.w = f2bf(v0.w);
    p1.x = f2bf(v1.x); p1.y = f2bf(v1.y); p1.z = f2bf(v1.z); p1.w = f2bf(v1.w);
    unsigned short* dst = &Alds[((c * 16 + ks_e) * 64 + lq) * 8];
    *(ushort4*)dst = p0;
    *(ushort4*)(dst + 4) = p1;
  }
  {  // ht gather from leaf stash (rows 0..63)
    const int rblk = tid >> 4, q = tid & 15;
    const int i = rblk >> 4, j = rblk & 15;
    const int gp = g0 + i * 63 + 32 + j;
    const int ch0 = i * 32 + 2 * j, ch1 = ch0 + 1;
    const int ty0 = ctype[2 * gp], ty1 = ctype[2 * gp + 1];
    const float c0 = cmask[2 * gp], c1 = cmask[2 * gp + 1];
    const float w00 = (ty0 == 0) ? c0 : 0.f, w01 = (ty1 == 0) ? c1 : 0.f;
    const float w10 = (ty0 == 1) ? c0 : 0.f, w11 = (ty1 == 1) ? c1 : 0.f;
    const int jc = q * 8;
    const u16x8 va = *(const u16x8*)&hstash[ch0 * 128 + jc];
    const u16x8 vb = *(const u16x8*)&hstash[ch1 * 128 + jc];
    u16x8 o0, o1;
#pragma unroll
    for (int e = 0; e < 8; ++e) {
      const float fa = bf2f(va[e]), fb = bf2f(vb[e]);
      o0[e] = f2bf(w00 * fa + w01 * fb);
      o1[e] = f2bf(w10 * fa + w11 * fb);
    }
    *(u16x8*)&Alds[a_addr<16>(rblk, 256 + jc)] = o0;
    *(u16x8*)&Alds[a_addr<16>(rblk, 384 + jc)] = o1;
  }
  __syncthreads();

  // ---- Phase 1 GEMM: MT=2, NT=5, slices 0..15 ----
  {
    f32x4 acc[2][5];
#pragma unroll
    for (int mt = 0; mt < 2; ++mt)
#pragma unroll
      for (int t = 0; t < 5; ++t) acc[mt][t] = (f32x4){0.f, 0.f, 0.f, 0.f};
    bf16x8 bA[5], bB[5];
#pragma unroll
    for (int t = 0; t < 5; ++t) bA[t] = *(const bf16x8*)&Bw[(size_t)t * 65536];
    auto step1 = [&](bf16x8(&cur)[5], bf16x8(&nxt)[5], int ks) {
      if (ks + 1 < 16) {
#pragma unroll
        for (int t = 0; t < 5; ++t)
          nxt[t] = *(const bf16x8*)&Bw[(size_t)t * 65536 + (ks + 1) * 512];
      }
      __builtin_amdgcn_s_setprio(1);
#pragma unroll
      for (int mt = 0; mt < 2; ++mt) {
        const bf16x8 a = *(const bf16x8*)&Alds[((mt * 16 + ks) * 64 + lane) << 3];
#pragma unroll
        for (int t = 0; t < 5; ++t)
          acc[mt][t] = __builtin_amdgcn_mfma_f32_16x16x32_bf16(a, cur[t], acc[mt][t], 0, 0, 0);
      }
      __builtin_amdgcn_s_setprio(0);
    };
#pragma unroll
    for (int ks2 = 0; ks2 < 8; ++ks2) {
      step1(bA, bB, 2 * ks2);
      step1(bB, bA, 2 * ks2 + 1);
    }
    // ---- Phase 1 epilogue: hoist leaf-c reads, then write + stash lvl1 ----
    float lc0[2][4], lc1[2][4];
#pragma unroll
    for (int mt = 0; mt < 2; ++mt) {
#pragma unroll
      for (int r = 0; r < 4; ++r) {
        const int row = (mt << 4) + rb + r;
        const int i = row >> 4, j = row & 15;
        const int ch0 = i * 32 + 2 * j;
        lc0[mt][r] = cstash[ch0 * 128 + hcol];
        lc1[mt][r] = cstash[(ch0 + 1) * 128 + hcol];
      }
    }
    __builtin_amdgcn_sched_barrier(0);   // all leaf-c reads before any stash write

    const float bi = b_iou[hcol], bo = b_iou[128 + hcol], bu = b_iou[256 + hcol];
    const float f0b = ufb[hcol], f1b = ufb[128 + hcol], bfv = bf_[hcol];
#pragma unroll
    for (int mt = 0; mt < 2; ++mt) {
#pragma unroll
      for (int r = 0; r < 4; ++r) {
        const int row = (mt << 4) + rb + r;       // 0..31
        const int i = row >> 4, j = row & 15;
        const int g = g0 + i * 63 + 32 + j;
        const int ty0 = ctype[2 * g], ty1 = ctype[2 * g + 1];
        const float c0v = cmask[2 * g], c1v = cmask[2 * g + 1];
        const float iv = acc[mt][0][r] + bi;
        const float ov = acc[mt][1][r] + bo;
        const float uv = acc[mt][2][r] + bu;
        const float f0 = acc[mt][3][r] + f0b;
        const float f1 = acc[mt][4][r] + f1b;
        const float fa = (ty0 == 0) ? f0 : f1;
        const float fb = (ty1 == 0) ? f0 : f1;
        const float ft0 = sigf(fa + bfv);
        const float ft1 = sigf(fb + bfv);
        const float ccell = ft0 * lc0[mt][r] * c0v + ft1 * lc1[mt][r] * c1v;
        const float cn = sigf(iv) * tanhfast(uv) + ccell;
        const float hn = sigf(ov) * tanhfast(cn);
        hout[(size_t)g * 128 + hcol] = hn;
        hstash[row * 128 + hcol] = f2bf(hn);      // lvl1 -> stash rows 0..31
        cstash[row * 128 + hcol] = cn;
      }
    }
  }
  __syncthreads();   // lvl1 stash visible

  // ---- Phase 2 staging: 16 lvl2 rows, K=512 fragment image ----
  {  // emb part: 16 rows x 32 subs = 512 threads exactly
    const int rblk = tid >> 5, sub = tid & 31;
    const int g = g0 + (rblk >> 3) * 63 + 48 + (rblk & 7);
    const int k0 = sub * 8;
    const float4 v0 = *(const float4*)&emb[(size_t)g * 256 + k0];
    const float4 v1 = *(const float4*)&emb[(size_t)g * 256 + k0 + 4];
    ushort4 p0, p1;
    p0.x = f2bf(v0.x); p0.y = f2bf(v0.y); p0.z = f2bf(v0.z); p0.w = f2bf(v0.w);
    p1.x = f2bf(v1.x); p1.y = f2bf(v1.y); p1.z = f2bf(v1.z); p1.w = f2bf(v1.w);
    unsigned short* dst = &Alds[a_addr<16>(rblk, k0)];
    *(ushort4*)dst = p0;
    *(ushort4*)(dst + 4) = p1;
  }
  if (tid < 256) {   // ht gather from lvl1 stash (rows 0..31)
    const int rblk = tid >> 4, q = tid & 15;
    const int i = rblk >> 3, j = rblk & 7;
    const int gp = g0 + i * 63 + 48 + j;
    const int ch0 = i * 16 + 2 * j, ch1 = ch0 + 1;
    const int ty0 = ctype[2 * gp], ty1 = ctype[2 * gp + 1];
    const float c0 = cmask[2 * gp], c1 = cmask[2 * gp + 1];
    const float w00 = (ty0 == 0) ? c0 : 0.f, w01 = (ty1 == 0) ? c1 : 0.f;
    const float w10 = (ty0 == 1) ? c0 : 0.f, w11 = (ty1 == 1) ? c1 : 0.f;
    const int jc = q * 8;
    const u16x8 va = *(const u16x8*)&hstash[ch0 * 128 + jc];
    const u16x8 vb = *(const u16x8*)&hstash[ch1 * 128 + jc];
    u16x8 o0, o1;
#pragma unroll
    for (int e = 0; e < 8; ++e) {
      const float fa = bf2f(va[e]), fb = bf2f(vb[e]);
      o0[e] = f2bf(w00 * fa + w01 * fb);
      o1[e] = f2bf(w10 * fa + w11 * fb);
    }
    *(u16x8*)&Alds[a_addr<16>(rblk, 256 + jc)] = o0;
    *(u16x8*)&Alds[a_addr<16>(rblk, 384 + jc)] = o1;
  }
  __syncthreads();

  // ---- Phase 2 GEMM: MT=1, NT=5, slices 0..15 ----
  {
    f32x4 acc[1][5];
#pragma unroll
    for (int t = 0; t < 5; ++t) acc[0][t] = (f32x4){0.f, 0.f, 0.f, 0.f};
    bf16x8 bA[5], bB[5];
#pragma unroll
    for (int t = 0; t < 5; ++t) bA[t] = *(const bf16x8*)&Bw[(size_t)t * 65536];
    auto step2 = [&](bf16x8(&cur)[5], bf16x8(&nxt)[5], int ks) {
      if (ks + 1 < 16) {
#pragma unroll
        for (int t = 0; t < 5; ++t)
          nxt[t] = *(const bf16x8*)&Bw[(size_t)t * 65536 + (ks + 1) * 512];
      }
      __builtin_amdgcn_s_setprio(1);
      const bf16x8 a = *(const bf16x8*)&Alds[(ks * 64 + lane) << 3];
#pragma unroll
      for (int t = 0; t < 5; ++t)
        acc[0][t] = __builtin_amdgcn_mfma_f32_16x16x32_bf16(a, cur[t], acc[0][t], 0, 0, 0);
      __builtin_amdgcn_s_setprio(0);
    };
#pragma unroll
    for (int ks2 = 0; ks2 < 8; ++ks2) {
      step2(bA, bB, 2 * ks2);
      step2(bB, bA, 2 * ks2 + 1);
    }
    // ---- Phase 2 epilogue: no stash writes (last phase) ----
    const float bi = b_iou[hcol], bo = b_iou[128 + hcol], bu = b_iou[256 + hcol];
    const float f0b = ufb[hcol], f1b = ufb[128 + hcol], bfv = bf_[hcol];
#pragma unroll
    for (int r = 0; r < 4; ++r) {
      const int row = rb + r;                    // 0..15
      const int i = row >> 3, j = row & 7;
      const int g = g0 + i * 63 + 48 + j;
      const int ch0 = i * 16 + 2 * j, ch1 = ch0 + 1;
      const int ty0 = ctype[2 * g], ty1 = ctype[2 * g + 1];
      const float c0v = cmask[2 * g], c1v = cmask[2 * g + 1];
      const float iv = acc[0][0][r] + bi;
      const float ov = acc[0][1][r] + bo;
      const float uv = acc[0][2][r] + bu;
      const float f0 = acc[0][3][r] + f0b;
      const float f1 = acc[0][4][r] + f1b;
      const float fa = (ty0 == 0) ? f0 : f1;
      const float fb = (ty1 == 0) ? f0 : f1;
      const float ft0 = sigf(fa + bfv);
      const float ft1 = sigf(fb + bfv);
      const float ccell = ft0 * cstash[ch0 * 128 + hcol] * c0v +
                          ft1 * cstash[ch1 * 128 + hcol] * c1v;
      const float cn = sigf(iv) * tanhfast(uv) + ccell;
      const float hn = sigf(ov) * tanhfast(cn);
      cbuf[(size_t)g * 128 + hcol] = cn;   // read by lvl3 tail
      hout[(size_t)g * 128 + hcol] = hn;
    }
  }
}

// ======================= tail levels (R12/R15 verbatim) ====================
template <bool LEAF, int MT, int WPE>
__global__ __launch_bounds__(512, WPE) void lvl_kernel(
    const float* __restrict__ emb, const float* __restrict__ cmask,
    const int* __restrict__ cidx, const int* __restrict__ ctype,
    const unsigned short* __restrict__ BTf,
    const float* __restrict__ b_iou, const float* __restrict__ ufb,
    const float* __restrict__ bf_,
    float* __restrict__ hout, float* __restrict__ cbuf,
    int lc, int cntm1, int offs) {
  constexpr int KD = LEAF ? 256 : 512;
  constexpr int NKS = KD / 32;
  constexpr int NT = LEAF ? 3 : 5;
  constexpr int ROWS = MT * 16;
  __shared__ unsigned short Alds[ROWS * KD];

  const int tid = threadIdx.x;
  const int lane = tid & 63;
  const int w = tid >> 6;
  const int m0 = blockIdx.x * ROWS;

#pragma unroll
  for (int c = 0; c < MT; ++c) {
    const int ks_e = tid >> 6;
    const int lq = tid & 63;
    const int k0 = ks_e * 32 + (lq >> 4) * 8;
    const int rblk = c * 16 + (lq & 15);
    const int m = m0 + rblk;
    const int g = ((m >> lc) * 63) + offs + (m & cntm1);
    const float4 v0 = *(const float4*)&emb[(size_t)g * 256 + k0];
    const float4 v1 = *(const float4*)&emb[(size_t)g * 256 + k0 + 4];
    ushort4 p0, p1;
    p0.x = f2bf(v0.x); p0.y = f2bf(v0.y); p0.z = f2bf(v0.z); p0.w = f2bf(v0.w);
    p1.x = f2bf(v1.x); p1.y = f2bf(v1.y); p1.z = f2bf(v1.z); p1.w = f2bf(v1.w);
    unsigned short* dst = &Alds[((c * NKS + ks_e) * 64 + lq) * 8];
    *(ushort4*)dst = p0;
    *(ushort4*)(dst + 4) = p1;
  }

  if (!LEAF) {
    constexpr int TPR = 512 / ROWS;
    constexpr int CPT = 128 / TPR;
    const int rblk = tid / TPR, q = tid % TPR;
    const int m = m0 + rblk;
    const int g = ((m >> lc) * 63) + offs + (m & cntm1);
    const int ch0 = cidx[2 * g], ch1 = cidx[2 * g + 1];
    const int ty0 = ctype[2 * g], ty1 = ctype[2 * g + 1];
    const float c0 = cmask[2 * g], c1 = cmask[2 * g + 1];
    const float w00 = (ty0 == 0) ? c0 : 0.f, w01 = (ty1 == 0) ? c1 : 0.f;
    const float w10 = (ty0 == 1) ? c0 : 0.f, w11 = (ty1 == 1) ? c1 : 0.f;
#pragma unroll
    for (int jj = 0; jj < CPT / 4; ++jj) {
      const int j = q * CPT + jj * 4;
      float4 a = *(const float4*)&hout[(size_t)ch0 * 128 + j];
      float4 b = *(const float4*)&hout[(size_t)ch1 * 128 + j];
      ushort4 p0, p1;
      p0.x = f2bf(w00 * a.x + w01 * b.x);
      p0.y = f2bf(w00 * a.y + w01 * b.y);
      p0.z = f2bf(w00 * a.z + w01 * b.z);
      p0.w = f2bf(w00 * a.w + w01 * b.w);
      p1.x = f2bf(w10 * a.x + w11 * b.x);
      p1.y = f2bf(w10 * a.y + w11 * b.y);
      p1.z = f2bf(w10 * a.z + w11 * b.z);
      p1.w = f2bf(w10 * a.w + w11 * b.w);
      *(ushort4*)&Alds[a_addr<NKS>(rblk, 256 + j)] = p0;
      *(ushort4*)&Alds[a_addr<NKS>(rblk, 384 + j)] = p1;
    }
  }
  __syncthreads();

  f32x4 acc[MT][NT];
#pragma unroll
  for (int mt = 0; mt < MT; ++mt)
#pragma unroll
    for (int t = 0; t < NT; ++t) acc[mt][t] = (f32x4){0.f, 0.f, 0.f, 0.f};

  const unsigned short* Bw = BTf + (size_t)w * 8192 + lane * 8;
  bf16x8 bA[NT], bB[NT];
#pragma unroll
  for (int t = 0; t < NT; ++t)
    bA[t] = *(const bf16x8*)&Bw[(size_t)t * 65536];

  auto step = [&](bf16x8(&cur)[NT], bf16x8(&nxt)[NT], int ks) {
    if (ks + 1 < NKS) {
#pragma unroll
      for (int t = 0; t < NT; ++t)
        nxt[t] = *(const bf16x8*)&Bw[(size_t)t * 65536 + (ks + 1) * 512];
    }
    __builtin_amdgcn_s_setprio(1);
#pragma unroll
    for (int mt = 0; mt < MT; ++mt) {
      const bf16x8 a = *(const bf16x8*)&Alds[((mt * NKS + ks) * 64 + lane) << 3];
#pragma unroll
      for (int t = 0; t < NT; ++t)
        acc[mt][t] = __builtin_amdgcn_mfma_f32_16x16x32_bf16(a, cur[t], acc[mt][t], 0, 0, 0);
    }
    __builtin_amdgcn_s_setprio(0);
  };
#pragma unroll
  for (int ks2 = 0; ks2 < NKS / 2; ++ks2) {
    step(bA, bB, 2 * ks2);
    step(bB, bA, 2 * ks2 + 1);
  }

  const int cl = lane & 15;
  const int rb = (lane >> 4) << 2;
  const int hcol = w * 16 + cl;
  const float bi = b_iou[hcol];
  const float bo = b_iou[128 + hcol];
  const float bu = b_iou[256 + hcol];
  float f0b = 0.f, f1b = 0.f, bfv = 0.f;
  if (!LEAF) { f0b = ufb[hcol]; f1b = ufb[128 + hcol]; bfv = bf_[hcol]; }

#pragma unroll
  for (int mt = 0; mt < MT; ++mt) {
#pragma unroll
    for (int r = 0; r < 4; ++r) {
      const int m = m0 + (mt << 4) + rb + r;
      const int g = ((m >> lc) * 63) + offs + (m & cntm1);
      const float iv = acc[mt][0][r] + bi;
      const float ov = acc[mt][1][r] + bo;
      const float uv = acc[mt][2][r] + bu;
      float cn;
      if (LEAF) {
        cn = sigf(iv) * tanhfast(uv);
      } else {
        const int ch0 = cidx[2 * g], ch1 = cidx[2 * g + 1];
        const int ty0 = ctype[2 * g], ty1 = ctype[2 * g + 1];
        const float c0v = cmask[2 * g], c1v = cmask[2 * g + 1];
        const float f0 = acc[mt][3][r] + f0b;
        const float f1 = acc[mt][4][r] + f1b;
        const float fa = (ty0 == 0) ? f0 : f1;
        const float fb = (ty1 == 0) ? f0 : f1;
        const float ft0 = sigf(fa + bfv);
        const float ft1 = sigf(fb + bfv);
        const float ccell = ft0 * cbuf[(size_t)ch0 * 128 + hcol] * c0v +
                            ft1 * cbuf[(size_t)ch1 * 128 + hcol] * c1v;
        cn = sigf(iv) * tanhfast(uv) + ccell;
      }
      const float hn = sigf(ov) * tanhfast(cn);
      cbuf[(size_t)g * 128 + hcol] = cn;
      hout[(size_t)g * 128 + hcol] = hn;
    }
  }
}

extern "C" void kernel_launch(void* const* d_in, const int* in_sizes, int n_in,
                              void* d_out, int out_size, void* d_ws, size_t ws_size,
                              hipStream_t stream) {
  (void)in_sizes; (void)n_in; (void)out_size; (void)ws_size;
  const float* emb   = (const float*)d_in[0];
  const float* cmask = (const float*)d_in[1];
  const float* W_iou = (const float*)d_in[2];
  const float* U_iou = (const float*)d_in[3];
  const float* b_iou = (const float*)d_in[4];
  const float* W_f   = (const float*)d_in[5];
  const float* U_f_w = (const float*)d_in[6];
  const float* U_f_b = (const float*)d_in[7];
  const float* b_f   = (const float*)d_in[8];
  const int* cidx    = (const int*)d_in[9];
  const int* ctype   = (const int*)d_in[10];
  float* hout = (float*)d_out;

  unsigned short* BTf = (unsigned short*)d_ws;                // 655360 B
  float* cbuf = (float*)((char*)d_ws + (size_t)(1 << 20));    // 132 MB

  prep_kernel<<<1280, 256, 0, stream>>>(W_iou, U_iou, W_f, U_f_w, BTf);

  // {leaf, lvl1, lvl2}: 2 trees/block
  fused_kernel<<<2048, 512, 0, stream>>>(emb, cmask, ctype, BTf, b_iou,
                                         U_f_b, b_f, hout, cbuf);
  // levels 3..5
  lvl_kernel<false, 2, 4><<<512, 512, 0, stream>>>(emb, cmask, cidx, ctype, BTf, b_iou,
                                                   U_f_b, b_f, hout, cbuf, 2, 3, 56);
  lvl_kernel<false, 1, 4><<<512, 512, 0, stream>>>(emb, cmask, cidx, ctype, BTf, b_iou,
                                                   U_f_b, b_f, hout, cbuf, 1, 1, 60);
  lvl_kernel<false, 1, 4><<<256, 512, 0, stream>>>(emb, cmask, cidx, ctype, BTf, b_iou,
                                                   U_f_b, b_f, hout, cbuf, 0, 0, 62);
}

// Round 19
// 268.734 us; speedup vs baseline: 1.7757x; 1.4879x over previous
//
#include <hip/hip_runtime.h>

// ---------------------------------------------------------------------------
// DepTreeLSTM on MI355X — round 19: lock in the R13 champion (266 us).
// fused_kernel: block = 2 trees (64 leaves + 32 lvl1 nodes), 2048 blocks.
//   Phase 0: leaf GEMM (MT=4, K=256, NT=3) + LSTM epilogue.
//            h -> hout(HBM) + LDS hstash(bf16); c -> LDS cstash(f32) ONLY.
//   Phase 1: lvl1 GEMM (MT=2, K=512, NT=5). ht from hstash, c_cell from
//            cstash (children are in-block by topology). h,c -> HBM.
// Tails lvl2..5: R12's lvl_kernel (B streamed to registers, ping-pong).
// NOTE: 3-phase variants spill to scratch (R14/R16/R18, +400MB WRITE_SIZE);
// 2 GEMM phases per kernel is this compiler's cliff. Do not add phases.
// LDS: A 32K + hstash 16K + cstash 32K = 80 KB -> 2 blocks/CU.
// ws: BTf bf16 fragment-packed at 0; c-state f32 [N][128] at 1MB.
// ---------------------------------------------------------------------------

typedef float f32x4 __attribute__((ext_vector_type(4)));
typedef __bf16 bf16x8 __attribute__((ext_vector_type(8)));
typedef unsigned short u16x8 __attribute__((ext_vector_type(8)));

__device__ __forceinline__ unsigned short f2bf(float x) {
  unsigned int u = __float_as_uint(x);
  return (unsigned short)((u + 0x7fffu + ((u >> 16) & 1u)) >> 16);
}
__device__ __forceinline__ float bf2f(unsigned short u) {
  return __uint_as_float(((unsigned int)u) << 16);
}
__device__ __forceinline__ float sigf(float x) { return 1.f / (1.f + __expf(-x)); }
__device__ __forceinline__ float tanhfast(float x) {
  return 1.f - 2.f / (__expf(2.f * x) + 1.f);
}

// Pack B in fragment order: BTf[((tile*16 + ks)*64 + lane)*8 + j]
// lane = kq*16 + cl, col = tile*16+cl, k = ks*32 + kq*8 + j  (K=512).
// col<384: W_iou/U_iou; col>=384: W_f (dup f0/f1) / U_f_w.
__global__ void prep_kernel(const float* __restrict__ Wi, const float* __restrict__ Ui,
                            const float* __restrict__ Wf, const float* __restrict__ Uf,
                            unsigned short* __restrict__ BTf) {
  int idx = blockIdx.x * 256 + threadIdx.x;
  int j = idx & 7;
  int lane = (idx >> 3) & 63;
  int ks = (idx >> 9) & 15;
  int tile = idx >> 13;
  int cl = lane & 15, kq = lane >> 4;
  int col = tile * 16 + cl;
  int k = ks * 32 + kq * 8 + j;
  float v;
  if (k < 256) {
    v = (col < 384) ? Wi[k * 384 + col] : Wf[k * 128 + ((col - 384) & 127)];
  } else {
    int kk = k & 255;
    v = (col < 384) ? Ui[kk * 384 + col] : Uf[kk * 256 + (col - 384)];
  }
  BTf[idx] = f2bf(v);
}

// A-LDS fragment-order address (elements): ((mt*NKS + ks)*64 + kq*16 + r)*8 + j
template <int NKS>
__device__ __forceinline__ int a_addr(int rblk, int k) {
  int mt = rblk >> 4, r = rblk & 15;
  int ks = k >> 5, kq = (k >> 3) & 3, j = k & 7;
  return (((mt * NKS + ks) * 64 + (kq << 4) + r) << 3) + j;
}

// ======================= fused leaf + lvl1 kernel ==========================
__global__ __launch_bounds__(512, 4) void fused_kernel(
    const float* __restrict__ emb, const float* __restrict__ cmask,
    const int* __restrict__ ctype,
    const unsigned short* __restrict__ BTf,
    const float* __restrict__ b_iou, const float* __restrict__ ufb,
    const float* __restrict__ bf_,
    float* __restrict__ hout, float* __restrict__ cbuf) {
  __shared__ unsigned short Alds[16384];   // 32 KB: leaf 64xK256 / lvl1 32xK512
  __shared__ unsigned short hstash[8192];  // 16 KB: 64 leaves x 128 bf16
  __shared__ float cstash[8192];           // 32 KB: 64 leaves x 128 f32

  const int tid = threadIdx.x;
  const int lane = tid & 63;
  const int w = tid >> 6;
  const int cl = lane & 15;
  const int rb = (lane >> 4) << 2;
  const int hcol = w * 16 + cl;
  const int g0 = blockIdx.x * 126;       // two trees: 2b, 2b+1

  const unsigned short* Bw = BTf + (size_t)w * 8192 + lane * 8;

  // ---- Phase 0 staging: 64 leaf emb rows, fragment image (NKS=8) ----
#pragma unroll
  for (int c = 0; c < 4; ++c) {
    const int ks_e = tid >> 6;
    const int lq = tid & 63;
    const int k0 = ks_e * 32 + (lq >> 4) * 8;
    const int rblk = c * 16 + (lq & 15);
    const int g = g0 + (rblk >> 5) * 63 + (rblk & 31);
    const float4 v0 = *(const float4*)&emb[(size_t)g * 256 + k0];
    const float4 v1 = *(const float4*)&emb[(size_t)g * 256 + k0 + 4];
    ushort4 p0, p1;
    p0.x = f2bf(v0.x); p0.y = f2bf(v0.y); p0.z = f2bf(v0.z); p0.w = f2bf(v0.w);
    p1.x = f2bf(v1.x); p1.y = f2bf(v1.y); p1.z = f2bf(v1.z); p1.w = f2bf(v1.w);
    unsigned short* dst = &Alds[((c * 8 + ks_e) * 64 + lq) * 8];
    *(ushort4*)dst = p0;
    *(ushort4*)(dst + 4) = p1;
  }
  __syncthreads();

  // ---- Phase 0 GEMM: MT=4, NT=3, slices 0..7 ----
  {
    f32x4 acc[4][3];
#pragma unroll
    for (int mt = 0; mt < 4; ++mt)
#pragma unroll
      for (int t = 0; t < 3; ++t) acc[mt][t] = (f32x4){0.f, 0.f, 0.f, 0.f};
    bf16x8 bA[3], bB[3];
#pragma unroll
    for (int t = 0; t < 3; ++t) bA[t] = *(const bf16x8*)&Bw[(size_t)t * 65536];
#pragma unroll
    for (int ks2 = 0; ks2 < 4; ++ks2) {
#pragma unroll
      for (int half = 0; half < 2; ++half) {
        const int ks = 2 * ks2 + half;
        bf16x8* cur = half ? bB : bA;
        bf16x8* nxt = half ? bA : bB;
        if (ks + 1 < 8) {
#pragma unroll
          for (int t = 0; t < 3; ++t)
            nxt[t] = *(const bf16x8*)&Bw[(size_t)t * 65536 + (ks + 1) * 512];
        }
        __builtin_amdgcn_s_setprio(1);
#pragma unroll
        for (int mt = 0; mt < 4; ++mt) {
          const bf16x8 a = *(const bf16x8*)&Alds[((mt * 8 + ks) * 64 + lane) << 3];
#pragma unroll
          for (int t = 0; t < 3; ++t)
            acc[mt][t] = __builtin_amdgcn_mfma_f32_16x16x32_bf16(a, cur[t], acc[mt][t], 0, 0, 0);
        }
        __builtin_amdgcn_s_setprio(0);
      }
    }
    // ---- Phase 0 epilogue: h->hout+hstash, c->cstash only ----
    const float bi = b_iou[hcol], bo = b_iou[128 + hcol], bu = b_iou[256 + hcol];
#pragma unroll
    for (int mt = 0; mt < 4; ++mt) {
#pragma unroll
      for (int r = 0; r < 4; ++r) {
        const int row = (mt << 4) + rb + r;
        const int g = g0 + (row >> 5) * 63 + (row & 31);
        const float cn = sigf(acc[mt][0][r] + bi) * tanhfast(acc[mt][2][r] + bu);
        const float hn = sigf(acc[mt][1][r] + bo) * tanhfast(cn);
        hout[(size_t)g * 128 + hcol] = hn;
        hstash[row * 128 + hcol] = f2bf(hn);
        cstash[row * 128 + hcol] = cn;
      }
    }
  }
  __syncthreads();   // stash visible; Alds free for reuse

  // ---- Phase 1 staging: 32 lvl1 rows, K=512 fragment image (NKS=16) ----
  // emb part (k<256)
#pragma unroll
  for (int c = 0; c < 2; ++c) {
    const int ks_e = tid >> 6;
    const int lq = tid & 63;
    const int k0 = ks_e * 32 + (lq >> 4) * 8;
    const int rblk = c * 16 + (lq & 15);
    const int g = g0 + (rblk >> 4) * 63 + 32 + (rblk & 15);
    const float4 v0 = *(const float4*)&emb[(size_t)g * 256 + k0];
    const float4 v1 = *(const float4*)&emb[(size_t)g * 256 + k0 + 4];
    ushort4 p0, p1;
    p0.x = f2bf(v0.x); p0.y = f2bf(v0.y); p0.z = f2bf(v0.z); p0.w = f2bf(v0.w);
    p1.x = f2bf(v1.x); p1.y = f2bf(v1.y); p1.z = f2bf(v1.z); p1.w = f2bf(v1.w);
    unsigned short* dst = &Alds[((c * 16 + ks_e) * 64 + lq) * 8];
    *(ushort4*)dst = p0;
    *(ushort4*)(dst + 4) = p1;
  }
  // ht part (k 256..511) from hstash: 16 threads/row, 8 cols each
  {
    const int rblk = tid >> 4, q = tid & 15;
    const int i = rblk >> 4, j = rblk & 15;
    const int gp = g0 + i * 63 + 32 + j;
    const int ch0 = i * 32 + 2 * j, ch1 = ch0 + 1;     // leaf stash rows
    const int ty0 = ctype[2 * gp], ty1 = ctype[2 * gp + 1];
    const float c0 = cmask[2 * gp], c1 = cmask[2 * gp + 1];
    const float w00 = (ty0 == 0) ? c0 : 0.f, w01 = (ty1 == 0) ? c1 : 0.f;
    const float w10 = (ty0 == 1) ? c0 : 0.f, w11 = (ty1 == 1) ? c1 : 0.f;
    const int jc = q * 8;
    const u16x8 va = *(const u16x8*)&hstash[ch0 * 128 + jc];
    const u16x8 vb = *(const u16x8*)&hstash[ch1 * 128 + jc];
    u16x8 o0, o1;
#pragma unroll
    for (int e = 0; e < 8; ++e) {
      const float fa = bf2f(va[e]), fb = bf2f(vb[e]);
      o0[e] = f2bf(w00 * fa + w01 * fb);
      o1[e] = f2bf(w10 * fa + w11 * fb);
    }
    *(u16x8*)&Alds[a_addr<16>(rblk, 256 + jc)] = o0;
    *(u16x8*)&Alds[a_addr<16>(rblk, 384 + jc)] = o1;
  }
  __syncthreads();

  // ---- Phase 1 GEMM: MT=2, NT=5, slices 0..15 ----
  {
    f32x4 acc[2][5];
#pragma unroll
    for (int mt = 0; mt < 2; ++mt)
#pragma unroll
      for (int t = 0; t < 5; ++t) acc[mt][t] = (f32x4){0.f, 0.f, 0.f, 0.f};
    bf16x8 bA[5], bB[5];
#pragma unroll
    for (int t = 0; t < 5; ++t) bA[t] = *(const bf16x8*)&Bw[(size_t)t * 65536];
#pragma unroll
    for (int ks2 = 0; ks2 < 8; ++ks2) {
#pragma unroll
      for (int half = 0; half < 2; ++half) {
        const int ks = 2 * ks2 + half;
        bf16x8* cur = half ? bB : bA;
        bf16x8* nxt = half ? bA : bB;
        if (ks + 1 < 16) {
#pragma unroll
          for (int t = 0; t < 5; ++t)
            nxt[t] = *(const bf16x8*)&Bw[(size_t)t * 65536 + (ks + 1) * 512];
        }
        __builtin_amdgcn_s_setprio(1);
#pragma unroll
        for (int mt = 0; mt < 2; ++mt) {
          const bf16x8 a = *(const bf16x8*)&Alds[((mt * 16 + ks) * 64 + lane) << 3];
#pragma unroll
          for (int t = 0; t < 5; ++t)
            acc[mt][t] = __builtin_amdgcn_mfma_f32_16x16x32_bf16(a, cur[t], acc[mt][t], 0, 0, 0);
        }
        __builtin_amdgcn_s_setprio(0);
      }
    }
    // ---- Phase 1 epilogue: full LSTM with stash c; h,c -> HBM ----
    const float bi = b_iou[hcol], bo = b_iou[128 + hcol], bu = b_iou[256 + hcol];
    const float f0b = ufb[hcol], f1b = ufb[128 + hcol], bfv = bf_[hcol];
#pragma unroll
    for (int mt = 0; mt < 2; ++mt) {
#pragma unroll
      for (int r = 0; r < 4; ++r) {
        const int row = (mt << 4) + rb + r;
        const int i = row >> 4, j = row & 15;
        const int g = g0 + i * 63 + 32 + j;
        const int ch0 = i * 32 + 2 * j, ch1 = ch0 + 1;
        const int ty0 = ctype[2 * g], ty1 = ctype[2 * g + 1];
        const float c0v = cmask[2 * g], c1v = cmask[2 * g + 1];
        const float iv = acc[mt][0][r] + bi;
        const float ov = acc[mt][1][r] + bo;
        const float uv = acc[mt][2][r] + bu;
        const float f0 = acc[mt][3][r] + f0b;
        const float f1 = acc[mt][4][r] + f1b;
        const float fa = (ty0 == 0) ? f0 : f1;
        const float fb = (ty1 == 0) ? f0 : f1;
        const float ft0 = sigf(fa + bfv);
        const float ft1 = sigf(fb + bfv);
        const float ccell = ft0 * cstash[ch0 * 128 + hcol] * c0v +
                            ft1 * cstash[ch1 * 128 + hcol] * c1v;
        const float cn = sigf(iv) * tanhfast(uv) + ccell;
        const float hn = sigf(ov) * tanhfast(cn);
        cbuf[(size_t)g * 128 + hcol] = cn;
        hout[(size_t)g * 128 + hcol] = hn;
      }
    }
  }
}

// ======================= tail levels (R12 verbatim) ========================
template <bool LEAF, int MT, int WPE>
__global__ __launch_bounds__(512, WPE) void lvl_kernel(
    const float* __restrict__ emb, const float* __restrict__ cmask,
    const int* __restrict__ cidx, const int* __restrict__ ctype,
    const unsigned short* __restrict__ BTf,
    const float* __restrict__ b_iou, const float* __restrict__ ufb,
    const float* __restrict__ bf_,
    float* __restrict__ hout, float* __restrict__ cbuf,
    int lc, int cntm1, int offs) {
  constexpr int KD = LEAF ? 256 : 512;
  constexpr int NKS = KD / 32;
  constexpr int NT = LEAF ? 3 : 5;
  constexpr int ROWS = MT * 16;
  __shared__ unsigned short Alds[ROWS * KD];

  const int tid = threadIdx.x;
  const int lane = tid & 63;
  const int w = tid >> 6;
  const int m0 = blockIdx.x * ROWS;

#pragma unroll
  for (int c = 0; c < MT; ++c) {
    const int ks_e = tid >> 6;
    const int lq = tid & 63;
    const int k0 = ks_e * 32 + (lq >> 4) * 8;
    const int rblk = c * 16 + (lq & 15);
    const int m = m0 + rblk;
    const int g = ((m >> lc) * 63) + offs + (m & cntm1);
    const float4 v0 = *(const float4*)&emb[(size_t)g * 256 + k0];
    const float4 v1 = *(const float4*)&emb[(size_t)g * 256 + k0 + 4];
    ushort4 p0, p1;
    p0.x = f2bf(v0.x); p0.y = f2bf(v0.y); p0.z = f2bf(v0.z); p0.w = f2bf(v0.w);
    p1.x = f2bf(v1.x); p1.y = f2bf(v1.y); p1.z = f2bf(v1.z); p1.w = f2bf(v1.w);
    unsigned short* dst = &Alds[((c * NKS + ks_e) * 64 + lq) * 8];
    *(ushort4*)dst = p0;
    *(ushort4*)(dst + 4) = p1;
  }

  if (!LEAF) {
    constexpr int TPR = 512 / ROWS;
    constexpr int CPT = 128 / TPR;
    const int rblk = tid / TPR, q = tid % TPR;
    const int m = m0 + rblk;
    const int g = ((m >> lc) * 63) + offs + (m & cntm1);
    const int ch0 = cidx[2 * g], ch1 = cidx[2 * g + 1];
    const int ty0 = ctype[2 * g], ty1 = ctype[2 * g + 1];
    const float c0 = cmask[2 * g], c1 = cmask[2 * g + 1];
    const float w00 = (ty0 == 0) ? c0 : 0.f, w01 = (ty1 == 0) ? c1 : 0.f;
    const float w10 = (ty0 == 1) ? c0 : 0.f, w11 = (ty1 == 1) ? c1 : 0.f;
#pragma unroll
    for (int jj = 0; jj < CPT / 4; ++jj) {
      const int j = q * CPT + jj * 4;
      float4 a = *(const float4*)&hout[(size_t)ch0 * 128 + j];
      float4 b = *(const float4*)&hout[(size_t)ch1 * 128 + j];
      ushort4 p0, p1;
      p0.x = f2bf(w00 * a.x + w01 * b.x);
      p0.y = f2bf(w00 * a.y + w01 * b.y);
      p0.z = f2bf(w00 * a.z + w01 * b.z);
      p0.w = f2bf(w00 * a.w + w01 * b.w);
      p1.x = f2bf(w10 * a.x + w11 * b.x);
      p1.y = f2bf(w10 * a.y + w11 * b.y);
      p1.z = f2bf(w10 * a.z + w11 * b.z);
      p1.w = f2bf(w10 * a.w + w11 * b.w);
      *(ushort4*)&Alds[a_addr<NKS>(rblk, 256 + j)] = p0;
      *(ushort4*)&Alds[a_addr<NKS>(rblk, 384 + j)] = p1;
    }
  }
  __syncthreads();

  f32x4 acc[MT][NT];
#pragma unroll
  for (int mt = 0; mt < MT; ++mt)
#pragma unroll
    for (int t = 0; t < NT; ++t) acc[mt][t] = (f32x4){0.f, 0.f, 0.f, 0.f};

  const unsigned short* Bw = BTf + (size_t)w * 8192 + lane * 8;
  bf16x8 bA[NT], bB[NT];
#pragma unroll
  for (int t = 0; t < NT; ++t)
    bA[t] = *(const bf16x8*)&Bw[(size_t)t * 65536];

  auto step = [&](bf16x8(&cur)[NT], bf16x8(&nxt)[NT], int ks) {
    if (ks + 1 < NKS) {
#pragma unroll
      for (int t = 0; t < NT; ++t)
        nxt[t] = *(const bf16x8*)&Bw[(size_t)t * 65536 + (ks + 1) * 512];
    }
    __builtin_amdgcn_s_setprio(1);
#pragma unroll
    for (int mt = 0; mt < MT; ++mt) {
      const bf16x8 a = *(const bf16x8*)&Alds[((mt * NKS + ks) * 64 + lane) << 3];
#pragma unroll
      for (int t = 0; t < NT; ++t)
        acc[mt][t] = __builtin_amdgcn_mfma_f32_16x16x32_bf16(a, cur[t], acc[mt][t], 0, 0, 0);
    }
    __builtin_amdgcn_s_setprio(0);
  };
#pragma unroll
  for (int ks2 = 0; ks2 < NKS / 2; ++ks2) {
    step(bA, bB, 2 * ks2);
    step(bB, bA, 2 * ks2 + 1);
  }

  const int cl = lane & 15;
  const int rb = (lane >> 4) << 2;
  const int hcol = w * 16 + cl;
  const float bi = b_iou[hcol];
  const float bo = b_iou[128 + hcol];
  const float bu = b_iou[256 + hcol];
  float f0b = 0.f, f1b = 0.f, bfv = 0.f;
  if (!LEAF) { f0b = ufb[hcol]; f1b = ufb[128 + hcol]; bfv = bf_[hcol]; }

#pragma unroll
  for (int mt = 0; mt < MT; ++mt) {
#pragma unroll
    for (int r = 0; r < 4; ++r) {
      const int m = m0 + (mt << 4) + rb + r;
      const int g = ((m >> lc) * 63) + offs + (m & cntm1);
      const float iv = acc[mt][0][r] + bi;
      const float ov = acc[mt][1][r] + bo;
      const float uv = acc[mt][2][r] + bu;
      float cn;
      if (LEAF) {
        cn = sigf(iv) * tanhfast(uv);
      } else {
        const int ch0 = cidx[2 * g], ch1 = cidx[2 * g + 1];
        const int ty0 = ctype[2 * g], ty1 = ctype[2 * g + 1];
        const float c0v = cmask[2 * g], c1v = cmask[2 * g + 1];
        const float f0 = acc[mt][3][r] + f0b;
        const float f1 = acc[mt][4][r] + f1b;
        const float fa = (ty0 == 0) ? f0 : f1;
        const float fb = (ty1 == 0) ? f0 : f1;
        const float ft0 = sigf(fa + bfv);
        const float ft1 = sigf(fb + bfv);
        const float ccell = ft0 * cbuf[(size_t)ch0 * 128 + hcol] * c0v +
                            ft1 * cbuf[(size_t)ch1 * 128 + hcol] * c1v;
        cn = sigf(iv) * tanhfast(uv) + ccell;
      }
      const float hn = sigf(ov) * tanhfast(cn);
      cbuf[(size_t)g * 128 + hcol] = cn;
      hout[(size_t)g * 128 + hcol] = hn;
    }
  }
}

extern "C" void kernel_launch(void* const* d_in, const int* in_sizes, int n_in,
                              void* d_out, int out_size, void* d_ws, size_t ws_size,
                              hipStream_t stream) {
  (void)in_sizes; (void)n_in; (void)out_size; (void)ws_size;
  const float* emb   = (const float*)d_in[0];
  const float* cmask = (const float*)d_in[1];
  const float* W_iou = (const float*)d_in[2];
  const float* U_iou = (const float*)d_in[3];
  const float* b_iou = (const float*)d_in[4];
  const float* W_f   = (const float*)d_in[5];
  const float* U_f_w = (const float*)d_in[6];
  const float* U_f_b = (const float*)d_in[7];
  const float* b_f   = (const float*)d_in[8];
  const int* cidx    = (const int*)d_in[9];
  const int* ctype   = (const int*)d_in[10];
  float* hout = (float*)d_out;

  unsigned short* BTf = (unsigned short*)d_ws;                // 655360 B
  float* cbuf = (float*)((char*)d_ws + (size_t)(1 << 20));    // N*128*4 = 132 MB

  prep_kernel<<<1280, 256, 0, stream>>>(W_iou, U_iou, W_f, U_f_w, BTf);

  // leaf + lvl1 fused: 2 trees per block
  fused_kernel<<<2048, 512, 0, stream>>>(emb, cmask, ctype, BTf, b_iou,
                                         U_f_b, b_f, hout, cbuf);
  // levels 2..5 (R12 tails)
  lvl_kernel<false, 2, 4><<<1024, 512, 0, stream>>>(emb, cmask, cidx, ctype, BTf, b_iou,
                                                    U_f_b, b_f, hout, cbuf, 3, 7, 48);
  lvl_kernel<false, 2, 4><<<512, 512, 0, stream>>>(emb, cmask, cidx, ctype, BTf, b_iou,
                                                   U_f_b, b_f, hout, cbuf, 2, 3, 56);
  lvl_kernel<false, 1, 4><<<512, 512, 0, stream>>>(emb, cmask, cidx, ctype, BTf, b_iou,
                                                   U_f_b, b_f, hout, cbuf, 1, 1, 60);
  lvl_kernel<false, 1, 4><<<256, 512, 0, stream>>>(emb, cmask, cidx, ctype, BTf, b_iou,
                                                   U_f_b, b_f, hout, cbuf, 0, 0, 62);
}